// Round 8
// baseline (933.303 us; speedup 1.0000x reference)
//
#include <hip/hip_runtime.h>
#include <cstdint>

// DecoderLayer on MI355X. R15 = R14 (891us) + scheduling-only changes:
// (1) SWZ: bijective XCD swizzle bid'=(bid&7)*(nb/8)+(bid>>3) on all big GEMMs
//     -> each XCD's L2 holds its own z-slices' working set (S slice = 2MB).
// (2) DIAG (self-PV): yt=(y+z)%16 breaks the 1:16 per-CU load imbalance from
//     the causal Keff clamp (launch-order CU assignment gave each CU same-y).
// Math identical to R14; only block->tile permutations changed.
// Footprint byte-identical to the proven 222,298,112 B layout.

typedef __bf16 bf16;
typedef __bf16 bf16x8 __attribute__((ext_vector_type(8)));
typedef float f32x4 __attribute__((ext_vector_type(4)));
typedef int i32x4 __attribute__((ext_vector_type(4)));
typedef int i32x8 __attribute__((ext_vector_type(8)));
typedef unsigned short u16;

static constexpr int Bb = 4, Ls = 2048, Es = 512, Hh = 8, Dd = 512, Ff = 2048;
static constexpr long BL = (long)Bb * Ls;
static constexpr int BIG = 1 << 30;

#define DEV __device__ __forceinline__

DEV u16 f2bf(float x) {  // RNE fp32 -> bf16
  unsigned u = __float_as_uint(x);
  return (u16)((u + 0x7fffu + ((u >> 16) & 1u)) >> 16);
}

DEV void async16(const void* gp, void* lp) {
  __builtin_amdgcn_global_load_lds(
      (const __attribute__((address_space(1))) void*)gp,
      (__attribute__((address_space(3))) void*)lp, 16, 0, 0);
}

// ---------------- GEMM: C[M,N] = act(alpha * A[M,K] @ Bt[N,K]^T + bias) ----------------
// z mapping (BYTE strides):
//   A  += (z/dA)*sA + ((z%mA)/dAi)*sAi
//   Bt += (z%mB)*sB + (z/dB)*sB2
//   C  += (z/dC)*sC + (z%mC)*sCi        ; transposed store when (z%mC) >= tz
//   RS  = rsum + z*M
// IN8: A,B fp8 e4m3 via MX-scaled MFMA K=128 (unit scales); else bf16.
// O8: fp8 stores on OUT=1/SM=1 paths (else bf16).
// OUT: 0=f32 store (+resid), 1=bf16/fp8 store.
// SM: 0=none, 1=store exp(alpha*s) + rowsum atomics, 2=scale by alpha/rowsum.
// CAUSAL: SM==1 -> mask col>row (TRI grid covers x<=y); SM==2 -> Keff=min(K,m0+128).
// TRI: packed triangular grid (gxy = T(T+1)/2), decode x<=y.
// SWZ: bijective XCD swizzle of the linear block id (requires nb%8==0).
// DIAG: yt=(yt+z)%gridDim.y load-balance remap (causal-PV).
template <int OUT, int SM, int IN8, int O8, bool BIAS, bool RELU, bool CAUSAL, bool RESID,
          bool TRI, bool SWZ, bool DIAG>
__global__ __launch_bounds__(256) void gemm128(
    const void* __restrict__ A, const void* __restrict__ Bt, void* __restrict__ Cout,
    const float* __restrict__ bias, const float* __restrict__ resid,
    float* __restrict__ rsum,
    int M, int N, int K, int lda, int ldb, int ldc, int ldct, int tz,
    long sA, int dA, long sAi, int mA, int dAi,
    long sB, int mB, long sB2, int dB,
    long sC, int dC, long sCi, int mC, float alpha) {
  unsigned bid = blockIdx.x + gridDim.x * (blockIdx.y + gridDim.y * blockIdx.z);
  if (SWZ) {
    const unsigned nb = gridDim.x * gridDim.y * gridDim.z;
    bid = (bid & 7u) * (nb >> 3) + (bid >> 3);
  }
  const unsigned gxy = gridDim.x * gridDim.y;
  const int z = (int)(bid / gxy);
  const unsigned rem = bid - (unsigned)z * gxy;
  int xt, yt;
  if (TRI) {
    const int bx = (int)rem;
    int y = (int)((sqrtf(8.0f * bx + 1.0f) - 1.0f) * 0.5f);
    while ((y + 1) * (y + 2) / 2 <= bx) ++y;
    while (y * (y + 1) / 2 > bx) --y;
    yt = y; xt = bx - y * (y + 1) / 2;
  } else {
    yt = (int)(rem / gridDim.x);
    xt = (int)(rem - (unsigned)yt * gridDim.x);
    if (DIAG) yt = (int)((unsigned)(yt + z) % gridDim.y);
  }
  const int m0 = yt * 128, n0 = xt * 128;
  int Keff = K;
  if (CAUSAL && SM == 2) { int kl = m0 + 128; Keff = kl < K ? kl : K; }

  const char* Ab = (const char*)A + (long)(z / dA) * sA + (long)((z % mA) / dAi) * sAi;
  const char* Bbp = (const char*)Bt + (long)(z % mB) * sB + (long)(z / dB) * sB2;
  char* Cb = (char*)Cout + (long)(z / dC) * sC + (long)(z % mC) * sCi;
  float* RS = (SM != 0) ? (rsum + (long)z * M) : nullptr;
  const int zc = z % mC;

  constexpr int ES = IN8 ? 1 : 2;                // bytes per element
  constexpr int KS = IN8 ? 128 : 64;             // elements per K-step (128 B either way)
  const long lasA = (long)lda * ES, lasB = (long)ldb * ES;

  __shared__ char As[16384];
  __shared__ char Bs[16384];

  const int tid = threadIdx.x;
  const int lane = tid & 63;
  const int quad = lane >> 4, r = lane & 15;
  const int wave = tid >> 6;
  const int wm = (wave >> 1) * 64, wn = (wave & 1) * 64;

  f32x4 acc[4][4];
  const f32x4 zero = {0.f, 0.f, 0.f, 0.f};
#pragma unroll
  for (int i = 0; i < 4; ++i)
#pragma unroll
    for (int j = 0; j < 4; ++j) acc[i][j] = zero;

  for (int k0 = 0; k0 < Keff; k0 += KS) {
    // unified staging: 128 rows x 128 B; 1024 chunks of 16B; slot s = (c&7)^(row&7)
#pragma unroll
    for (int i = 0; i < 4; ++i) {
      const int c = i * 256 + tid, row = c >> 3;
      const int s = (c & 7) ^ (row & 7);
      async16(Ab + (long)(m0 + row) * lasA + ((long)k0 * ES + s * 16), As + c * 16);
    }
#pragma unroll
    for (int i = 0; i < 4; ++i) {
      const int c = i * 256 + tid, row = c >> 3;
      const int s = (c & 7) ^ (row & 7);
      async16(Bbp + (long)(n0 + row) * lasB + ((long)k0 * ES + s * 16), Bs + c * 16);
    }
    asm volatile("s_waitcnt vmcnt(0)" ::: "memory");
    __syncthreads();

    if (IN8) {
      // MX fp8: lane (quad,r) holds k bytes [quad*32, quad*32+32) of row wm+t*16+r
      i32x8 af[4], bw[4];
#pragma unroll
      for (int t = 0; t < 4; ++t) {
        const int Ra = wm + t * 16 + r;
        const char* pa = As + Ra * 128;
        i32x4 alo = *(const i32x4*)(pa + (((2 * quad) ^ (Ra & 7)) * 16));
        i32x4 ahi = *(const i32x4*)(pa + (((2 * quad + 1) ^ (Ra & 7)) * 16));
        af[t] = __builtin_shufflevector(alo, ahi, 0, 1, 2, 3, 4, 5, 6, 7);
        const int Rb = wn + t * 16 + r;
        const char* pb = Bs + Rb * 128;
        i32x4 blo = *(const i32x4*)(pb + (((2 * quad) ^ (Rb & 7)) * 16));
        i32x4 bhi = *(const i32x4*)(pb + (((2 * quad + 1) ^ (Rb & 7)) * 16));
        bw[t] = __builtin_shufflevector(blo, bhi, 0, 1, 2, 3, 4, 5, 6, 7);
      }
#pragma unroll
      for (int i = 0; i < 4; ++i)
#pragma unroll
        for (int j = 0; j < 4; ++j)
          acc[i][j] = __builtin_amdgcn_mfma_scale_f32_16x16x128_f8f6f4(
              af[i], bw[j], acc[i][j], 0, 0, 0, 0x7f7f7f7f, 0, 0x7f7f7f7f);
    } else {
#pragma unroll
      for (int u = 0; u < 2; ++u) {
        bf16x8 af[4], bw[4];
#pragma unroll
        for (int t = 0; t < 4; ++t) {
          const int Ra = wm + t * 16 + r;
          af[t] = *(const bf16x8*)(As + Ra * 128 + (((u * 4 + quad) ^ (Ra & 7)) * 16));
          const int Rb = wn + t * 16 + r;
          bw[t] = *(const bf16x8*)(Bs + Rb * 128 + (((u * 4 + quad) ^ (Rb & 7)) * 16));
        }
#pragma unroll
        for (int i = 0; i < 4; ++i)
#pragma unroll
          for (int j = 0; j < 4; ++j)
            acc[i][j] = __builtin_amdgcn_mfma_f32_16x16x32_bf16(af[i], bw[j], acc[i][j], 0, 0, 0);
      }
    }
    __syncthreads();
  }

  // epilogue: C/D layout col = lane&15, row = quad*4 + reg
#pragma unroll
  for (int i = 0; i < 4; ++i) {
    const int rowb = m0 + wm + i * 16 + quad * 4;
    if (SM == 1) {
      float rpart[4] = {0.f, 0.f, 0.f, 0.f};
#pragma unroll
      for (int j = 0; j < 4; ++j) {
        const int col = n0 + wn + j * 16 + r;
#pragma unroll
        for (int t = 0; t < 4; ++t) {
          float p = __expf(acc[i][j][t] * alpha);
          if (CAUSAL && col > rowb + t) p = 0.f;
          rpart[t] += p;
          if (O8) {
            int w8 = __builtin_amdgcn_cvt_pk_fp8_f32(p, p, 0, false);
            Cb[(long)(rowb + t) * ldc + col] = (char)(w8 & 0xff);
          } else {
            ((u16*)Cb)[(long)(rowb + t) * ldc + col] = f2bf(p);
          }
        }
      }
#pragma unroll
      for (int t = 0; t < 4; ++t) {
        rpart[t] += __shfl_xor(rpart[t], 1);
        rpart[t] += __shfl_xor(rpart[t], 2);
        rpart[t] += __shfl_xor(rpart[t], 4);
        rpart[t] += __shfl_xor(rpart[t], 8);
      }
      if (r == 0) {
#pragma unroll
        for (int t = 0; t < 4; ++t) atomicAdd(RS + rowb + t, rpart[t]);
      }
      continue;
    }
    float rinv[4];
    if (SM == 2) {
#pragma unroll
      for (int t = 0; t < 4; ++t) rinv[t] = alpha / RS[rowb + t];
    }
#pragma unroll
    for (int j = 0; j < 4; ++j) {
      const int col = n0 + wn + j * 16 + r;
      float v[4];
#pragma unroll
      for (int t = 0; t < 4; ++t)
        v[t] = (SM == 2) ? acc[i][j][t] * rinv[t] : acc[i][j][t] * alpha;
      if (BIAS) {
        const float bb = bias[col];
#pragma unroll
        for (int t = 0; t < 4; ++t) v[t] += bb;
      }
      if (RELU) {
#pragma unroll
        for (int t = 0; t < 4; ++t) v[t] = fmaxf(v[t], 0.f);
      }
      if (OUT == 0) {
        float* C = (float*)Cb;
#pragma unroll
        for (int t = 0; t < 4; ++t) {
          long idx = (long)(rowb + t) * ldc + col;
          float o = v[t];
          if (RESID) o += resid[idx];
          C[idx] = o;
        }
      } else {
        if (zc >= tz) {  // transposed store C[col][rowb..rowb+3]
          if (O8) {
            int w8 = __builtin_amdgcn_cvt_pk_fp8_f32(v[0], v[1], 0, false);
            w8 = __builtin_amdgcn_cvt_pk_fp8_f32(v[2], v[3], w8, true);
            *(int*)(Cb + (long)col * ldct + rowb) = w8;
          } else {
            ushort4 p;
            p.x = f2bf(v[0]); p.y = f2bf(v[1]); p.z = f2bf(v[2]); p.w = f2bf(v[3]);
            *(ushort4*)((u16*)Cb + (long)col * ldct + rowb) = p;
          }
        } else {  // row-major
#pragma unroll
          for (int t = 0; t < 4; ++t) {
            if (O8) {
              int w8 = __builtin_amdgcn_cvt_pk_fp8_f32(v[t], v[t], 0, false);
              Cb[(long)(rowb + t) * ldc + col] = (char)(w8 & 0xff);
            } else {
              ((u16*)Cb)[(long)(rowb + t) * ldc + col] = f2bf(v[t]);
            }
          }
        }
      }
    }
  }
}

// ---------------- LayerNorm (E=512): one wave per row; F8: fp8 out, else bf16 ----------------
template <int F8>
__global__ __launch_bounds__(256) void ln_kernel(
    const float* __restrict__ x, const float* __restrict__ g, const float* __restrict__ be,
    void* __restrict__ y, float* __restrict__ xcopy, int nrows) {
  const int wave = threadIdx.x >> 6, lane = threadIdx.x & 63;
  const long row = (long)blockIdx.x * 4 + wave;
  const float4* xr = (const float4*)(x + row * 512);
  float4 v0 = xr[lane], v1 = xr[lane + 64];
  if (xcopy) {
    float4* c = (float4*)(xcopy + row * 512);
    c[lane] = v0; c[lane + 64] = v1;
  }
  float s = v0.x + v0.y + v0.z + v0.w + v1.x + v1.y + v1.z + v1.w;
#pragma unroll
  for (int o = 32; o >= 1; o >>= 1) s += __shfl_xor(s, o);
  const float m = s * (1.0f / 512.0f);
  float d = (v0.x - m) * (v0.x - m) + (v0.y - m) * (v0.y - m) + (v0.z - m) * (v0.z - m) +
            (v0.w - m) * (v0.w - m) + (v1.x - m) * (v1.x - m) + (v1.y - m) * (v1.y - m) +
            (v1.z - m) * (v1.z - m) + (v1.w - m) * (v1.w - m);
#pragma unroll
  for (int o = 32; o >= 1; o >>= 1) d += __shfl_xor(d, o);
  const float rstd = rsqrtf(d * (1.0f / 512.0f) + 1e-5f);
  const float4* gv = (const float4*)g;
  const float4* bv = (const float4*)be;
  float4 g0 = gv[lane], g1 = gv[lane + 64], b0 = bv[lane], b1 = bv[lane + 64];
  float n0 = (v0.x - m) * rstd * g0.x + b0.x, n1 = (v0.y - m) * rstd * g0.y + b0.y;
  float n2 = (v0.z - m) * rstd * g0.z + b0.z, n3 = (v0.w - m) * rstd * g0.w + b0.w;
  float n4 = (v1.x - m) * rstd * g1.x + b1.x, n5 = (v1.y - m) * rstd * g1.y + b1.y;
  float n6 = (v1.z - m) * rstd * g1.z + b1.z, n7 = (v1.w - m) * rstd * g1.w + b1.w;
  if (F8) {
    char* yr = (char*)y + row * 512;
    int w0 = __builtin_amdgcn_cvt_pk_fp8_f32(n0, n1, 0, false);
    w0 = __builtin_amdgcn_cvt_pk_fp8_f32(n2, n3, w0, true);
    int w1 = __builtin_amdgcn_cvt_pk_fp8_f32(n4, n5, 0, false);
    w1 = __builtin_amdgcn_cvt_pk_fp8_f32(n6, n7, w1, true);
    *(int*)(yr + 4 * lane) = w0;
    *(int*)(yr + 256 + 4 * lane) = w1;
  } else {
    uint2 o0, o1;
    o0.x = (unsigned)f2bf(n0) | ((unsigned)f2bf(n1) << 16);
    o0.y = (unsigned)f2bf(n2) | ((unsigned)f2bf(n3) << 16);
    o1.x = (unsigned)f2bf(n4) | ((unsigned)f2bf(n5) << 16);
    o1.y = (unsigned)f2bf(n6) | ((unsigned)f2bf(n7) << 16);
    uint2* yr = (uint2*)((u16*)y + row * 512);
    yr[lane] = o0; yr[lane + 64] = o1;
  }
}

// ---------------- fp32 -> fp8 convert ----------------
__global__ __launch_bounds__(256) void cvt_fp8_kernel(const float* __restrict__ x,
                                                      char* __restrict__ y, long n) {
  long i = ((long)blockIdx.x * 256 + threadIdx.x) * 8;
  if (i >= n) return;
  float4 a = *(const float4*)(x + i), b = *(const float4*)(x + i + 4);
  int w0 = __builtin_amdgcn_cvt_pk_fp8_f32(a.x, a.y, 0, false);
  w0 = __builtin_amdgcn_cvt_pk_fp8_f32(a.z, a.w, w0, true);
  int w1 = __builtin_amdgcn_cvt_pk_fp8_f32(b.x, b.y, 0, false);
  w1 = __builtin_amdgcn_cvt_pk_fp8_f32(b.z, b.w, w1, true);
  int2 o; o.x = w0; o.y = w1;
  *(int2*)(y + i) = o;
}

// ---------------- zero fp32 buffer ----------------
__global__ __launch_bounds__(256) void zero_kernel(float* __restrict__ p) {
  long i = ((long)blockIdx.x * 256 + threadIdx.x) * 4;
  const float4 z4 = {0.f, 0.f, 0.f, 0.f};
  *(float4*)(p + i) = z4;
}

// ---------------- transpose 6 attn weight sets fp32 [E,D] -> fp8 [D,E], x64 scale ----------------
__global__ __launch_bounds__(256) void transpose6(
    const float* __restrict__ s0, const float* __restrict__ s1, const float* __restrict__ s2,
    const float* __restrict__ s3, const float* __restrict__ s4, const float* __restrict__ s5,
    char* __restrict__ out) {
  __shared__ float t[32][33];
  const int set = blockIdx.z >> 3, head = blockIdx.z & 7;
  const float* in = set == 0 ? s0 : set == 1 ? s1 : set == 2 ? s2
                   : set == 3 ? s3 : set == 4 ? s4 : s5;
  const long sW = (long)Es * Dd;
  in += (long)head * sW;
  char* o = out + ((long)set * Hh + head) * sW;
  const int c0 = blockIdx.x * 32, r0 = blockIdx.y * 32;
  const int tx = threadIdx.x & 31, ty = threadIdx.x >> 5;
#pragma unroll
  for (int i = 0; i < 32; i += 8) t[ty + i][tx] = in[(long)(r0 + ty + i) * Dd + (c0 + tx)];
  __syncthreads();
#pragma unroll
  for (int i = 0; i < 32; i += 8) {
    float xv = t[tx][ty + i] * 64.0f;
    o[(long)(c0 + ty + i) * Es + (r0 + tx)] =
        (char)(__builtin_amdgcn_cvt_pk_fp8_f32(xv, xv, 0, false) & 0xff);
  }
}

// ---------------- transpose fp32 [R,C] -> fp8 [C,R], x64 scale ----------------
__global__ __launch_bounds__(256) void transpose_cvt8(const float* __restrict__ in,
                                                      char* __restrict__ out, int R, int C) {
  __shared__ float t[32][33];
  const int c0 = blockIdx.x * 32, r0 = blockIdx.y * 32;
  const int tx = threadIdx.x & 31, ty = threadIdx.x >> 5;
#pragma unroll
  for (int i = 0; i < 32; i += 8) t[ty + i][tx] = in[(long)(r0 + ty + i) * C + (c0 + tx)];
  __syncthreads();
#pragma unroll
  for (int i = 0; i < 32; i += 8) {
    float xv = t[tx][ty + i] * 64.0f;
    out[(long)(c0 + ty + i) * R + (r0 + tx)] =
        (char)(__builtin_amdgcn_cvt_pk_fp8_f32(xv, xv, 0, false) & 0xff);
  }
}

// ---------------- reduce 8 bf16 head slabs per batch: acc += sum_h O[b'][h] ----------------
__global__ __launch_bounds__(256) void reduce8b_kernel(const u16* __restrict__ O,
                                                       float* __restrict__ acc) {
  const long n = (long)Ls * Dd;  // per-slab elems
  const u16* Ob = O + (long)blockIdx.y * 8 * n;
  float* ab = acc + (long)blockIdx.y * (long)Ls * Es;
  long i = ((long)blockIdx.x * 256 + threadIdx.x) * 8;
  float s[8] = {0.f, 0.f, 0.f, 0.f, 0.f, 0.f, 0.f, 0.f};
#pragma unroll
  for (int h = 0; h < 8; ++h) {
    bf16x8 t = *(const bf16x8*)(Ob + (long)h * n + i);
#pragma unroll
    for (int e = 0; e < 8; ++e) s[e] += (float)t[e];
  }
  float4 a0 = *(const float4*)(ab + i);
  float4 a1 = *(const float4*)(ab + i + 4);
  a0.x += s[0]; a0.y += s[1]; a0.z += s[2]; a0.w += s[3];
  a1.x += s[4]; a1.y += s[5]; a1.z += s[6]; a1.w += s[7];
  *(float4*)(ab + i) = a0;
  *(float4*)(ab + i + 4) = a1;
}

// ---------------- finalize: out = slab0+slab1+slab2+slab3 + b2 + resid ----------------
__global__ __launch_bounds__(256) void finalize_kernel(const float* __restrict__ slabs,
                                                       const float* __restrict__ resid,
                                                       const float* __restrict__ b2,
                                                       float* __restrict__ out) {
  const long SL = (long)BL * Es;
  long i = ((long)blockIdx.x * 256 + threadIdx.x) * 4;
  float4 a0 = *(const float4*)(slabs + i);
  float4 a1 = *(const float4*)(slabs + SL + i);
  float4 a2 = *(const float4*)(slabs + 2 * SL + i);
  float4 a3 = *(const float4*)(slabs + 3 * SL + i);
  float4 rr = *(const float4*)(resid + i);
  float4 bb = *(const float4*)(b2 + (int)(i & 511));
  float4 o;
  o.x = a0.x + a1.x + a2.x + a3.x + rr.x + bb.x;
  o.y = a0.y + a1.y + a2.y + a3.y + rr.y + bb.y;
  o.z = a0.z + a1.z + a2.z + a3.z + rr.z + bb.z;
  o.w = a0.w + a1.w + a2.w + a3.w + rr.w + bb.w;
  *(float4*)(out + i) = o;
}

// ---------------- host ----------------
extern "C" void kernel_launch(void* const* d_in, const int* in_sizes, int n_in,
                              void* d_out, int out_size, void* d_ws, size_t ws_size,
                              hipStream_t stream) {
  const float* q = (const float*)d_in[0];
  const float* k = (const float*)d_in[1];
  const float* v = (const float*)d_in[2];
  const float* Wq_s = (const float*)d_in[3];
  const float* Wk_s = (const float*)d_in[4];
  const float* Wv_s = (const float*)d_in[5];
  const float* Wq_c = (const float*)d_in[6];
  const float* Wk_c = (const float*)d_in[7];
  const float* Wv_c = (const float*)d_in[8];
  const float* W1 = (const float*)d_in[9];
  const float* b1 = (const float*)d_in[10];
  const float* W2 = (const float*)d_in[11];
  const float* b2 = (const float*)d_in[12];
  const float* g1 = (const float*)d_in[13];
  const float* be1 = (const float*)d_in[14];
  const float* g2 = (const float*)d_in[15];
  const float* be2 = (const float*)d_in[16];
  const float* g3 = (const float*)d_in[17];
  const float* be3 = (const float*)d_in[18];

  char* w = (char*)d_ws;
  size_t off = 0;
  auto alloc = [&](size_t bytes) -> char* {
    char* p = w + off;
    off += (bytes + 255) & ~(size_t)255;
    return p;
  };
  const long sW = (long)Es * Dd;     // per-head weight elems (= bytes fp8)
  const long sQ = (long)Ls * Dd;     // per-head Q/K/Vt elems (= bytes fp8)
  const long sS = (long)Ls * Ls;     // per-head S elems (= bytes fp8)
  const long sBE = (long)Ls * Es;    // per-batch row-slab elems

  // footprint identical to proven layout: 222,298,112 bytes
  u16* Wqst = (u16*)alloc((size_t)Hh * sW * 2);   // 48 fp8 weight slabs live here
  u16* Wkst = (u16*)alloc((size_t)Hh * sW * 2);
  u16* Wvst = (u16*)alloc((size_t)Hh * sW * 2);
  u16* Wqct = (u16*)alloc((size_t)Hh * sW * 2);
  u16* Wkct = (u16*)alloc((size_t)Hh * sW * 2);
  u16* Wvct = (u16*)alloc((size_t)Hh * sW * 2);
  u16* W1t = (u16*)alloc((size_t)Es * Ff * 2);    // rowsum scratch during attention
  u16* W2t = (u16*)alloc((size_t)Es * Ff * 2);
  u16* qn = (u16*)alloc((size_t)BL * Es * 2);     // fp8 qn8 (4MB of 8)
  u16* knb = (u16*)alloc((size_t)BL * Es * 2);    // fp8 k (4MB of 8)
  u16* vnb = (u16*)alloc((size_t)BL * Es * 2);    // fp8 v (4MB of 8)
  char* QKV = alloc((size_t)Hh * sQ * 2);         // QKVp: 48MB = 2 batches x 24MB
  char* KVx = alloc((size_t)Hh * sQ * 2);         //   (Q 8 | K 8 | Vt 8 per batch)
  u16* Vtb = (u16*)alloc((size_t)Hh * sQ * 2);    //   region reused across pairs
  char* Sb = alloc((size_t)Hh * sS * 2);          // 64MB: pair S (2x32MB); FFN2 slabs later
  float* acc1 = (float*)alloc((size_t)BL * Es * 4);
  u16* hbuf = (u16*)alloc((size_t)BL * Ff * 2);   // 32MB: PV bf16 slabs; fp8 h later
  (void)KVx; (void)Vtb; (void)Wkst; (void)Wvst; (void)Wqct; (void)Wkct; (void)Wvct;
  char* QKVp = QKV;
  float* accF = (float*)Sb;   // FFN2 split-K slabs
  float* rsum = (float*)W1t;  // 64 rows x Ls fp32 = 512 KB (self 0..31, cross 32..63)
  char* Wq8 = (char*)Wqst;    // 48 contiguous fp8 head-slabs (x64-scaled)
  char* qn8 = (char*)qn;      // fp8 LN out; kb8/vb8 at +8MB/+16MB (alloc stride)
  char* W1t8 = (char*)W1t;    // fp8 FFN weights (x64), 1MB each
  char* W2t8 = (char*)W2t;
  char* h8 = (char*)hbuf;     // fp8 h (16MB of 32)
  const long tstr = (long)BL * Es * 2;  // 8MB alloc stride between qn/knb/vnb
  (void)in_sizes; (void)n_in; (void)out_size; (void)ws_size;

  const dim3 blk(256);
  transpose6<<<dim3(Dd / 32, Es / 32, 48), blk, 0, stream>>>(Wq_s, Wk_s, Wv_s, Wq_c, Wk_c, Wv_c, Wq8);
  cvt_fp8_kernel<<<dim3((unsigned)(BL * Es / 2048)), blk, 0, stream>>>(k, (char*)knb, BL * Es);
  cvt_fp8_kernel<<<dim3((unsigned)(BL * Es / 2048)), blk, 0, stream>>>(v, (char*)vnb, BL * Es);
  zero_kernel<<<dim3(8 * Hh * Ls / 1024), blk, 0, stream>>>(rsum);

  // LN1 (+ residual copy into acc1), fp8 out
  ln_kernel<1><<<dim3((unsigned)(BL / 4)), blk, 0, stream>>>(q, g1, be1, qn8, acc1, (int)BL);

  const float scl = 0.044194173824159216f;         // 512^-0.5
  const float sclS = scl / 4096.0f;                // weights x64 on both Q and K
  const float aPV = 0.125f / 64.0f;                // 1/H, V x64
  const float aW = 1.0f / 64.0f;                   // FFN weights x64
  const float* np = nullptr;

  // ---- self-attention (causal), per batch-pair p (batches 2p, 2p+1) ----
  for (int p = 0; p < 2; ++p) {
    const char* qp8 = qn8 + (long)p * 2 * sBE;     // pair base (2 batches x 1MB)
    float* rsS = rsum + (long)p * 16 * Ls;
    // pair projection: z = b'*24 + (type*8+h); C = b'*24MB + (z%24)*1MB; Vt transposed
    gemm128<1, 0, 1, 1, false, false, false, false, false, true, false><<<dim3(4, 16, 48), blk, 0, stream>>>(
        qp8, Wq8, QKVp, np, np, nullptr, Ls, Dd, Es, Es, Es, Dd, Ls, 16,
        sBE, 24, 0, 24, 8,        // A: (z/24)*1MB
        sW, 24, 0, 1,             // B: (z%24)*sW
        24 * sQ, 24, sQ, 24,      // C: (z/24)*24MB + (z%24)*1MB; tz vs z%24
        1.0f);
    // pair S causal: packed triangular grid (136 blocks/slice), z = b'*8 + h
    gemm128<1, 1, 1, 1, false, false, true, false, true, true, false><<<dim3(136, 1, 16), blk, 0, stream>>>(
        QKVp, QKVp + 8 * sQ, Sb, np, np, rsS, Ls, Ls, Dd, Dd, Dd, Ls, Ls, BIG,
        24 * sQ, 8, sQ, 8, 1,     // A: (z/8)*24MB + (z%8)*1MB
        sQ, 8, 24 * sQ, 8,        // B: (z%8)*1MB + (z/8)*24MB
        8 * sS, 8, sS, 8,         // C: (z/8)*32MB + (z%8)*4MB
        sclS);
    // pair PV (causal Keff clamp via SM==2), DIAG balance, bf16 slabs in hbuf
    gemm128<1, 2, 1, 0, false, false, true, false, false, true, true><<<dim3(4, 16, 16), blk, 0, stream>>>(
        Sb, QKVp + 16 * sQ, hbuf, np, np, rsS, Ls, Dd, Ls, Ls, Ls, Dd, Ls, BIG,
        8 * sS, 8, sS, 8, 1,      // A: (z/8)*32MB + (z%8)*4MB
        sQ, 8, 24 * sQ, 8,        // B: (z%8)*1MB + (z/8)*24MB
        8 * sQ * 2, 8, sQ * 2, 8, // C: (z/8)*16MB + (z%8)*2MB (bf16)
        aPV);
    reduce8b_kernel<<<dim3(512, 2), blk, 0, stream>>>(hbuf, acc1 + (long)p * 2 * sBE);
  }

  // LN2, fp8 out
  ln_kernel<1><<<dim3((unsigned)(BL / 4)), blk, 0, stream>>>(acc1, g2, be2, qn8, nullptr, (int)BL);

  // ---- cross-attention (non-causal), per batch-pair ----
  for (int p = 0; p < 2; ++p) {
    const char* qp8 = qn8 + (long)p * 2 * sBE;
    float* rsS = rsum + (long)(32 + p * 16) * Ls;
    // pair projection: A = pairbase + b'*1MB + type*8MB (type walks qn|knb|vnb)
    gemm128<1, 0, 1, 1, false, false, false, false, false, true, false><<<dim3(4, 16, 48), blk, 0, stream>>>(
        qp8, Wq8 + 24 * sW, QKVp, np, np, nullptr, Ls, Dd, Es, Es, Es, Dd, Ls, 16,
        sBE, 24, tstr, 24, 8,     // A: (z/24)*1MB + ((z%24)/8)*8MB
        sW, 24, 0, 1,
        24 * sQ, 24, sQ, 24,
        1.0f);
    gemm128<1, 1, 1, 1, false, false, false, false, false, true, false><<<dim3(16, 16, 16), blk, 0, stream>>>(
        QKVp, QKVp + 8 * sQ, Sb, np, np, rsS, Ls, Ls, Dd, Dd, Dd, Ls, Ls, BIG,
        24 * sQ, 8, sQ, 8, 1,
        sQ, 8, 24 * sQ, 8,
        8 * sS, 8, sS, 8,
        sclS);
    gemm128<1, 2, 1, 0, false, false, false, false, false, true, false><<<dim3(4, 16, 16), blk, 0, stream>>>(
        Sb, QKVp + 16 * sQ, hbuf, np, np, rsS, Ls, Dd, Ls, Ls, Ls, Dd, Ls, BIG,
        8 * sS, 8, sS, 8, 1,
        sQ, 8, 24 * sQ, 8,
        8 * sQ * 2, 8, sQ * 2, 8,
        aPV);
    reduce8b_kernel<<<dim3(512, 2), blk, 0, stream>>>(hbuf, acc1 + (long)p * 2 * sBE);
  }

  // FFN weights -> fp8 transposed x64 (rowsum scratch dead now)
  transpose_cvt8<<<dim3(Ff / 32, Es / 32, 1), blk, 0, stream>>>(W1, W1t8, Es, Ff);
  transpose_cvt8<<<dim3(Es / 32, Ff / 32, 1), blk, 0, stream>>>(W2, W2t8, Ff, Es);

  // LN3 (fp8) + FFN (MX fp8)
  ln_kernel<1><<<dim3((unsigned)(BL / 4)), blk, 0, stream>>>(acc1, g3, be3, qn8, nullptr, (int)BL);
  // FFN1: h = relu(x@W1/64 + b1), fp8 store
  gemm128<1, 0, 1, 1, true, true, false, false, false, true, false><<<dim3(Ff / 128, (unsigned)(BL / 128), 1), blk, 0, stream>>>(
      qn8, W1t8, h8, b1, np, nullptr, (int)BL, Ff, Es, Es, Es, Ff, Ff, BIG,
      0, 1, 0, 1, 1,
      0, 1, 0, 1,
      0, 1, 0, 1, aW);
  // FFN2: split-K=4 (512 elems each), fp32 slabs, alpha=1/64
  gemm128<0, 0, 1, 0, false, false, false, false, false, true, false><<<dim3(Es / 128, (unsigned)(BL / 128), 4), blk, 0, stream>>>(
      h8, W2t8, accF, np, np, nullptr, (int)BL, Es, 512, Ff, Ff, Es, Es, BIG,
      512, 1, 0, 1, 1,           // A: z*512 bytes (k-offset)
      0, 1, 512, 1,              // B: z*512 bytes (k-offset)
      (long)BL * Es * 4, 1, 0, 1,// C: z*slab
      aW);
  finalize_kernel<<<dim3((unsigned)(BL * Es / 1024)), blk, 0, stream>>>(accF, acc1, b2, (float*)d_out);
}

// Round 9
// 852.239 us; speedup vs baseline: 1.0951x; 1.0951x over previous
//
#include <hip/hip_runtime.h>
#include <cstdint>

// DecoderLayer on MI355X. R16 = R14 (891us, best) + DIAG only on self-PV.
// R15's XCD swizzle REVERTED: it cut cross-S FETCH 75->16.7MB (locality
// worked) but cost 72->96.5us — kernel is latency-bound, not HBM-bound, and
// single-XCD z-slices lost memory-level parallelism (atomics+writes on one L2).
// DIAG (self-PV): yt=(y+z)%16 breaks the 1:16 per-CU load imbalance from the
// causal Keff clamp. Math identical to R14.
// Footprint byte-identical to the proven 222,298,112 B layout.

typedef __bf16 bf16;
typedef __bf16 bf16x8 __attribute__((ext_vector_type(8)));
typedef float f32x4 __attribute__((ext_vector_type(4)));
typedef int i32x4 __attribute__((ext_vector_type(4)));
typedef int i32x8 __attribute__((ext_vector_type(8)));
typedef unsigned short u16;

static constexpr int Bb = 4, Ls = 2048, Es = 512, Hh = 8, Dd = 512, Ff = 2048;
static constexpr long BL = (long)Bb * Ls;
static constexpr int BIG = 1 << 30;

#define DEV __device__ __forceinline__

DEV u16 f2bf(float x) {  // RNE fp32 -> bf16
  unsigned u = __float_as_uint(x);
  return (u16)((u + 0x7fffu + ((u >> 16) & 1u)) >> 16);
}

DEV void async16(const void* gp, void* lp) {
  __builtin_amdgcn_global_load_lds(
      (const __attribute__((address_space(1))) void*)gp,
      (__attribute__((address_space(3))) void*)lp, 16, 0, 0);
}

// ---------------- GEMM: C[M,N] = act(alpha * A[M,K] @ Bt[N,K]^T + bias) ----------------
// z mapping (BYTE strides):
//   A  += (z/dA)*sA + ((z%mA)/dAi)*sAi
//   Bt += (z%mB)*sB + (z/dB)*sB2
//   C  += (z/dC)*sC + (z%mC)*sCi        ; transposed store when (z%mC) >= tz
//   RS  = rsum + z*M
// IN8: A,B fp8 e4m3 via MX-scaled MFMA K=128 (unit scales); else bf16.
// O8: fp8 stores on OUT=1/SM=1 paths (else bf16).
// OUT: 0=f32 store (+resid), 1=bf16/fp8 store.
// SM: 0=none, 1=store exp(alpha*s) + rowsum atomics, 2=scale by alpha/rowsum.
// CAUSAL: SM==1 -> mask col>row (TRI grid covers x<=y); SM==2 -> Keff=min(K,m0+128).
// TRI: packed triangular grid (gridDim.x = T(T+1)/2), decode x<=y.
// DIAG: yt=(yt+z)%gridDim.y load-balance remap (causal-PV).
template <int OUT, int SM, int IN8, int O8, bool BIAS, bool RELU, bool CAUSAL, bool RESID,
          bool TRI, bool DIAG>
__global__ __launch_bounds__(256) void gemm128(
    const void* __restrict__ A, const void* __restrict__ Bt, void* __restrict__ Cout,
    const float* __restrict__ bias, const float* __restrict__ resid,
    float* __restrict__ rsum,
    int M, int N, int K, int lda, int ldb, int ldc, int ldct, int tz,
    long sA, int dA, long sAi, int mA, int dAi,
    long sB, int mB, long sB2, int dB,
    long sC, int dC, long sCi, int mC, float alpha) {
  int xt, yt;
  if (TRI) {
    const int bx = blockIdx.x;
    int y = (int)((sqrtf(8.0f * bx + 1.0f) - 1.0f) * 0.5f);
    while ((y + 1) * (y + 2) / 2 <= bx) ++y;
    while (y * (y + 1) / 2 > bx) --y;
    yt = y; xt = bx - y * (y + 1) / 2;
  } else {
    xt = blockIdx.x; yt = blockIdx.y;
    if (DIAG) yt = (int)((unsigned)(yt + blockIdx.z) % gridDim.y);
  }
  const int m0 = yt * 128, n0 = xt * 128;
  int Keff = K;
  if (CAUSAL && SM == 2) { int kl = m0 + 128; Keff = kl < K ? kl : K; }

  const int z = blockIdx.z;
  const char* Ab = (const char*)A + (long)(z / dA) * sA + (long)((z % mA) / dAi) * sAi;
  const char* Bbp = (const char*)Bt + (long)(z % mB) * sB + (long)(z / dB) * sB2;
  char* Cb = (char*)Cout + (long)(z / dC) * sC + (long)(z % mC) * sCi;
  float* RS = (SM != 0) ? (rsum + (long)z * M) : nullptr;
  const int zc = z % mC;

  constexpr int ES = IN8 ? 1 : 2;                // bytes per element
  constexpr int KS = IN8 ? 128 : 64;             // elements per K-step (128 B either way)
  const long lasA = (long)lda * ES, lasB = (long)ldb * ES;

  __shared__ char As[16384];
  __shared__ char Bs[16384];

  const int tid = threadIdx.x;
  const int lane = tid & 63;
  const int quad = lane >> 4, r = lane & 15;
  const int wave = tid >> 6;
  const int wm = (wave >> 1) * 64, wn = (wave & 1) * 64;

  f32x4 acc[4][4];
  const f32x4 zero = {0.f, 0.f, 0.f, 0.f};
#pragma unroll
  for (int i = 0; i < 4; ++i)
#pragma unroll
    for (int j = 0; j < 4; ++j) acc[i][j] = zero;

  for (int k0 = 0; k0 < Keff; k0 += KS) {
    // unified staging: 128 rows x 128 B; 1024 chunks of 16B; slot s = (c&7)^(row&7)
#pragma unroll
    for (int i = 0; i < 4; ++i) {
      const int c = i * 256 + tid, row = c >> 3;
      const int s = (c & 7) ^ (row & 7);
      async16(Ab + (long)(m0 + row) * lasA + ((long)k0 * ES + s * 16), As + c * 16);
    }
#pragma unroll
    for (int i = 0; i < 4; ++i) {
      const int c = i * 256 + tid, row = c >> 3;
      const int s = (c & 7) ^ (row & 7);
      async16(Bbp + (long)(n0 + row) * lasB + ((long)k0 * ES + s * 16), Bs + c * 16);
    }
    asm volatile("s_waitcnt vmcnt(0)" ::: "memory");
    __syncthreads();

    if (IN8) {
      // MX fp8: lane (quad,r) holds k bytes [quad*32, quad*32+32) of row wm+t*16+r
      i32x8 af[4], bw[4];
#pragma unroll
      for (int t = 0; t < 4; ++t) {
        const int Ra = wm + t * 16 + r;
        const char* pa = As + Ra * 128;
        i32x4 alo = *(const i32x4*)(pa + (((2 * quad) ^ (Ra & 7)) * 16));
        i32x4 ahi = *(const i32x4*)(pa + (((2 * quad + 1) ^ (Ra & 7)) * 16));
        af[t] = __builtin_shufflevector(alo, ahi, 0, 1, 2, 3, 4, 5, 6, 7);
        const int Rb = wn + t * 16 + r;
        const char* pb = Bs + Rb * 128;
        i32x4 blo = *(const i32x4*)(pb + (((2 * quad) ^ (Rb & 7)) * 16));
        i32x4 bhi = *(const i32x4*)(pb + (((2 * quad + 1) ^ (Rb & 7)) * 16));
        bw[t] = __builtin_shufflevector(blo, bhi, 0, 1, 2, 3, 4, 5, 6, 7);
      }
#pragma unroll
      for (int i = 0; i < 4; ++i)
#pragma unroll
        for (int j = 0; j < 4; ++j)
          acc[i][j] = __builtin_amdgcn_mfma_scale_f32_16x16x128_f8f6f4(
              af[i], bw[j], acc[i][j], 0, 0, 0, 0x7f7f7f7f, 0, 0x7f7f7f7f);
    } else {
#pragma unroll
      for (int u = 0; u < 2; ++u) {
        bf16x8 af[4], bw[4];
#pragma unroll
        for (int t = 0; t < 4; ++t) {
          const int Ra = wm + t * 16 + r;
          af[t] = *(const bf16x8*)(As + Ra * 128 + (((u * 4 + quad) ^ (Ra & 7)) * 16));
          const int Rb = wn + t * 16 + r;
          bw[t] = *(const bf16x8*)(Bs + Rb * 128 + (((u * 4 + quad) ^ (Rb & 7)) * 16));
        }
#pragma unroll
        for (int i = 0; i < 4; ++i)
#pragma unroll
          for (int j = 0; j < 4; ++j)
            acc[i][j] = __builtin_amdgcn_mfma_f32_16x16x32_bf16(af[i], bw[j], acc[i][j], 0, 0, 0);
      }
    }
    __syncthreads();
  }

  // epilogue: C/D layout col = lane&15, row = quad*4 + reg
#pragma unroll
  for (int i = 0; i < 4; ++i) {
    const int rowb = m0 + wm + i * 16 + quad * 4;
    if (SM == 1) {
      float rpart[4] = {0.f, 0.f, 0.f, 0.f};
#pragma unroll
      for (int j = 0; j < 4; ++j) {
        const int col = n0 + wn + j * 16 + r;
#pragma unroll
        for (int t = 0; t < 4; ++t) {
          float p = __expf(acc[i][j][t] * alpha);
          if (CAUSAL && col > rowb + t) p = 0.f;
          rpart[t] += p;
          if (O8) {
            int w8 = __builtin_amdgcn_cvt_pk_fp8_f32(p, p, 0, false);
            Cb[(long)(rowb + t) * ldc + col] = (char)(w8 & 0xff);
          } else {
            ((u16*)Cb)[(long)(rowb + t) * ldc + col] = f2bf(p);
          }
        }
      }
#pragma unroll
      for (int t = 0; t < 4; ++t) {
        rpart[t] += __shfl_xor(rpart[t], 1);
        rpart[t] += __shfl_xor(rpart[t], 2);
        rpart[t] += __shfl_xor(rpart[t], 4);
        rpart[t] += __shfl_xor(rpart[t], 8);
      }
      if (r == 0) {
#pragma unroll
        for (int t = 0; t < 4; ++t) atomicAdd(RS + rowb + t, rpart[t]);
      }
      continue;
    }
    float rinv[4];
    if (SM == 2) {
#pragma unroll
      for (int t = 0; t < 4; ++t) rinv[t] = alpha / RS[rowb + t];
    }
#pragma unroll
    for (int j = 0; j < 4; ++j) {
      const int col = n0 + wn + j * 16 + r;
      float v[4];
#pragma unroll
      for (int t = 0; t < 4; ++t)
        v[t] = (SM == 2) ? acc[i][j][t] * rinv[t] : acc[i][j][t] * alpha;
      if (BIAS) {
        const float bb = bias[col];
#pragma unroll
        for (int t = 0; t < 4; ++t) v[t] += bb;
      }
      if (RELU) {
#pragma unroll
        for (int t = 0; t < 4; ++t) v[t] = fmaxf(v[t], 0.f);
      }
      if (OUT == 0) {
        float* C = (float*)Cb;
#pragma unroll
        for (int t = 0; t < 4; ++t) {
          long idx = (long)(rowb + t) * ldc + col;
          float o = v[t];
          if (RESID) o += resid[idx];
          C[idx] = o;
        }
      } else {
        if (zc >= tz) {  // transposed store C[col][rowb..rowb+3]
          if (O8) {
            int w8 = __builtin_amdgcn_cvt_pk_fp8_f32(v[0], v[1], 0, false);
            w8 = __builtin_amdgcn_cvt_pk_fp8_f32(v[2], v[3], w8, true);
            *(int*)(Cb + (long)col * ldct + rowb) = w8;
          } else {
            ushort4 p;
            p.x = f2bf(v[0]); p.y = f2bf(v[1]); p.z = f2bf(v[2]); p.w = f2bf(v[3]);
            *(ushort4*)((u16*)Cb + (long)col * ldct + rowb) = p;
          }
        } else {  // row-major
#pragma unroll
          for (int t = 0; t < 4; ++t) {
            if (O8) {
              int w8 = __builtin_amdgcn_cvt_pk_fp8_f32(v[t], v[t], 0, false);
              Cb[(long)(rowb + t) * ldc + col] = (char)(w8 & 0xff);
            } else {
              ((u16*)Cb)[(long)(rowb + t) * ldc + col] = f2bf(v[t]);
            }
          }
        }
      }
    }
  }
}

// ---------------- LayerNorm (E=512): one wave per row; F8: fp8 out, else bf16 ----------------
template <int F8>
__global__ __launch_bounds__(256) void ln_kernel(
    const float* __restrict__ x, const float* __restrict__ g, const float* __restrict__ be,
    void* __restrict__ y, float* __restrict__ xcopy, int nrows) {
  const int wave = threadIdx.x >> 6, lane = threadIdx.x & 63;
  const long row = (long)blockIdx.x * 4 + wave;
  const float4* xr = (const float4*)(x + row * 512);
  float4 v0 = xr[lane], v1 = xr[lane + 64];
  if (xcopy) {
    float4* c = (float4*)(xcopy + row * 512);
    c[lane] = v0; c[lane + 64] = v1;
  }
  float s = v0.x + v0.y + v0.z + v0.w + v1.x + v1.y + v1.z + v1.w;
#pragma unroll
  for (int o = 32; o >= 1; o >>= 1) s += __shfl_xor(s, o);
  const float m = s * (1.0f / 512.0f);
  float d = (v0.x - m) * (v0.x - m) + (v0.y - m) * (v0.y - m) + (v0.z - m) * (v0.z - m) +
            (v0.w - m) * (v0.w - m) + (v1.x - m) * (v1.x - m) + (v1.y - m) * (v1.y - m) +
            (v1.z - m) * (v1.z - m) + (v1.w - m) * (v1.w - m);
#pragma unroll
  for (int o = 32; o >= 1; o >>= 1) d += __shfl_xor(d, o);
  const float rstd = rsqrtf(d * (1.0f / 512.0f) + 1e-5f);
  const float4* gv = (const float4*)g;
  const float4* bv = (const float4*)be;
  float4 g0 = gv[lane], g1 = gv[lane + 64], b0 = bv[lane], b1 = bv[lane + 64];
  float n0 = (v0.x - m) * rstd * g0.x + b0.x, n1 = (v0.y - m) * rstd * g0.y + b0.y;
  float n2 = (v0.z - m) * rstd * g0.z + b0.z, n3 = (v0.w - m) * rstd * g0.w + b0.w;
  float n4 = (v1.x - m) * rstd * g1.x + b1.x, n5 = (v1.y - m) * rstd * g1.y + b1.y;
  float n6 = (v1.z - m) * rstd * g1.z + b1.z, n7 = (v1.w - m) * rstd * g1.w + b1.w;
  if (F8) {
    char* yr = (char*)y + row * 512;
    int w0 = __builtin_amdgcn_cvt_pk_fp8_f32(n0, n1, 0, false);
    w0 = __builtin_amdgcn_cvt_pk_fp8_f32(n2, n3, w0, true);
    int w1 = __builtin_amdgcn_cvt_pk_fp8_f32(n4, n5, 0, false);
    w1 = __builtin_amdgcn_cvt_pk_fp8_f32(n6, n7, w1, true);
    *(int*)(yr + 4 * lane) = w0;
    *(int*)(yr + 256 + 4 * lane) = w1;
  } else {
    uint2 o0, o1;
    o0.x = (unsigned)f2bf(n0) | ((unsigned)f2bf(n1) << 16);
    o0.y = (unsigned)f2bf(n2) | ((unsigned)f2bf(n3) << 16);
    o1.x = (unsigned)f2bf(n4) | ((unsigned)f2bf(n5) << 16);
    o1.y = (unsigned)f2bf(n6) | ((unsigned)f2bf(n7) << 16);
    uint2* yr = (uint2*)((u16*)y + row * 512);
    yr[lane] = o0; yr[lane + 64] = o1;
  }
}

// ---------------- fp32 -> fp8 convert ----------------
__global__ __launch_bounds__(256) void cvt_fp8_kernel(const float* __restrict__ x,
                                                      char* __restrict__ y, long n) {
  long i = ((long)blockIdx.x * 256 + threadIdx.x) * 8;
  if (i >= n) return;
  float4 a = *(const float4*)(x + i), b = *(const float4*)(x + i + 4);
  int w0 = __builtin_amdgcn_cvt_pk_fp8_f32(a.x, a.y, 0, false);
  w0 = __builtin_amdgcn_cvt_pk_fp8_f32(a.z, a.w, w0, true);
  int w1 = __builtin_amdgcn_cvt_pk_fp8_f32(b.x, b.y, 0, false);
  w1 = __builtin_amdgcn_cvt_pk_fp8_f32(b.z, b.w, w1, true);
  int2 o; o.x = w0; o.y = w1;
  *(int2*)(y + i) = o;
}

// ---------------- zero fp32 buffer ----------------
__global__ __launch_bounds__(256) void zero_kernel(float* __restrict__ p) {
  long i = ((long)blockIdx.x * 256 + threadIdx.x) * 4;
  const float4 z4 = {0.f, 0.f, 0.f, 0.f};
  *(float4*)(p + i) = z4;
}

// ---------------- transpose 6 attn weight sets fp32 [E,D] -> fp8 [D,E], x64 scale ----------------
__global__ __launch_bounds__(256) void transpose6(
    const float* __restrict__ s0, const float* __restrict__ s1, const float* __restrict__ s2,
    const float* __restrict__ s3, const float* __restrict__ s4, const float* __restrict__ s5,
    char* __restrict__ out) {
  __shared__ float t[32][33];
  const int set = blockIdx.z >> 3, head = blockIdx.z & 7;
  const float* in = set == 0 ? s0 : set == 1 ? s1 : set == 2 ? s2
                   : set == 3 ? s3 : set == 4 ? s4 : s5;
  const long sW = (long)Es * Dd;
  in += (long)head * sW;
  char* o = out + ((long)set * Hh + head) * sW;
  const int c0 = blockIdx.x * 32, r0 = blockIdx.y * 32;
  const int tx = threadIdx.x & 31, ty = threadIdx.x >> 5;
#pragma unroll
  for (int i = 0; i < 32; i += 8) t[ty + i][tx] = in[(long)(r0 + ty + i) * Dd + (c0 + tx)];
  __syncthreads();
#pragma unroll
  for (int i = 0; i < 32; i += 8) {
    float xv = t[tx][ty + i] * 64.0f;
    o[(long)(c0 + ty + i) * Es + (r0 + tx)] =
        (char)(__builtin_amdgcn_cvt_pk_fp8_f32(xv, xv, 0, false) & 0xff);
  }
}

// ---------------- transpose fp32 [R,C] -> fp8 [C,R], x64 scale ----------------
__global__ __launch_bounds__(256) void transpose_cvt8(const float* __restrict__ in,
                                                      char* __restrict__ out, int R, int C) {
  __shared__ float t[32][33];
  const int c0 = blockIdx.x * 32, r0 = blockIdx.y * 32;
  const int tx = threadIdx.x & 31, ty = threadIdx.x >> 5;
#pragma unroll
  for (int i = 0; i < 32; i += 8) t[ty + i][tx] = in[(long)(r0 + ty + i) * C + (c0 + tx)];
  __syncthreads();
#pragma unroll
  for (int i = 0; i < 32; i += 8) {
    float xv = t[tx][ty + i] * 64.0f;
    out[(long)(c0 + ty + i) * R + (r0 + tx)] =
        (char)(__builtin_amdgcn_cvt_pk_fp8_f32(xv, xv, 0, false) & 0xff);
  }
}

// ---------------- reduce 8 bf16 head slabs per batch: acc += sum_h O[b'][h] ----------------
__global__ __launch_bounds__(256) void reduce8b_kernel(const u16* __restrict__ O,
                                                       float* __restrict__ acc) {
  const long n = (long)Ls * Dd;  // per-slab elems
  const u16* Ob = O + (long)blockIdx.y * 8 * n;
  float* ab = acc + (long)blockIdx.y * (long)Ls * Es;
  long i = ((long)blockIdx.x * 256 + threadIdx.x) * 8;
  float s[8] = {0.f, 0.f, 0.f, 0.f, 0.f, 0.f, 0.f, 0.f};
#pragma unroll
  for (int h = 0; h < 8; ++h) {
    bf16x8 t = *(const bf16x8*)(Ob + (long)h * n + i);
#pragma unroll
    for (int e = 0; e < 8; ++e) s[e] += (float)t[e];
  }
  float4 a0 = *(const float4*)(ab + i);
  float4 a1 = *(const float4*)(ab + i + 4);
  a0.x += s[0]; a0.y += s[1]; a0.z += s[2]; a0.w += s[3];
  a1.x += s[4]; a1.y += s[5]; a1.z += s[6]; a1.w += s[7];
  *(float4*)(ab + i) = a0;
  *(float4*)(ab + i + 4) = a1;
}

// ---------------- finalize: out = slab0+slab1+slab2+slab3 + b2 + resid ----------------
__global__ __launch_bounds__(256) void finalize_kernel(const float* __restrict__ slabs,
                                                       const float* __restrict__ resid,
                                                       const float* __restrict__ b2,
                                                       float* __restrict__ out) {
  const long SL = (long)BL * Es;
  long i = ((long)blockIdx.x * 256 + threadIdx.x) * 4;
  float4 a0 = *(const float4*)(slabs + i);
  float4 a1 = *(const float4*)(slabs + SL + i);
  float4 a2 = *(const float4*)(slabs + 2 * SL + i);
  float4 a3 = *(const float4*)(slabs + 3 * SL + i);
  float4 rr = *(const float4*)(resid + i);
  float4 bb = *(const float4*)(b2 + (int)(i & 511));
  float4 o;
  o.x = a0.x + a1.x + a2.x + a3.x + rr.x + bb.x;
  o.y = a0.y + a1.y + a2.y + a3.y + rr.y + bb.y;
  o.z = a0.z + a1.z + a2.z + a3.z + rr.z + bb.z;
  o.w = a0.w + a1.w + a2.w + a3.w + rr.w + bb.w;
  *(float4*)(out + i) = o;
}

// ---------------- host ----------------
extern "C" void kernel_launch(void* const* d_in, const int* in_sizes, int n_in,
                              void* d_out, int out_size, void* d_ws, size_t ws_size,
                              hipStream_t stream) {
  const float* q = (const float*)d_in[0];
  const float* k = (const float*)d_in[1];
  const float* v = (const float*)d_in[2];
  const float* Wq_s = (const float*)d_in[3];
  const float* Wk_s = (const float*)d_in[4];
  const float* Wv_s = (const float*)d_in[5];
  const float* Wq_c = (const float*)d_in[6];
  const float* Wk_c = (const float*)d_in[7];
  const float* Wv_c = (const float*)d_in[8];
  const float* W1 = (const float*)d_in[9];
  const float* b1 = (const float*)d_in[10];
  const float* W2 = (const float*)d_in[11];
  const float* b2 = (const float*)d_in[12];
  const float* g1 = (const float*)d_in[13];
  const float* be1 = (const float*)d_in[14];
  const float* g2 = (const float*)d_in[15];
  const float* be2 = (const float*)d_in[16];
  const float* g3 = (const float*)d_in[17];
  const float* be3 = (const float*)d_in[18];

  char* w = (char*)d_ws;
  size_t off = 0;
  auto alloc = [&](size_t bytes) -> char* {
    char* p = w + off;
    off += (bytes + 255) & ~(size_t)255;
    return p;
  };
  const long sW = (long)Es * Dd;     // per-head weight elems (= bytes fp8)
  const long sQ = (long)Ls * Dd;     // per-head Q/K/Vt elems (= bytes fp8)
  const long sS = (long)Ls * Ls;     // per-head S elems (= bytes fp8)
  const long sBE = (long)Ls * Es;    // per-batch row-slab elems

  // footprint identical to proven layout: 222,298,112 bytes
  u16* Wqst = (u16*)alloc((size_t)Hh * sW * 2);   // 48 fp8 weight slabs live here
  u16* Wkst = (u16*)alloc((size_t)Hh * sW * 2);
  u16* Wvst = (u16*)alloc((size_t)Hh * sW * 2);
  u16* Wqct = (u16*)alloc((size_t)Hh * sW * 2);
  u16* Wkct = (u16*)alloc((size_t)Hh * sW * 2);
  u16* Wvct = (u16*)alloc((size_t)Hh * sW * 2);
  u16* W1t = (u16*)alloc((size_t)Es * Ff * 2);    // rowsum scratch during attention
  u16* W2t = (u16*)alloc((size_t)Es * Ff * 2);
  u16* qn = (u16*)alloc((size_t)BL * Es * 2);     // fp8 qn8 (4MB of 8)
  u16* knb = (u16*)alloc((size_t)BL * Es * 2);    // fp8 k (4MB of 8)
  u16* vnb = (u16*)alloc((size_t)BL * Es * 2);    // fp8 v (4MB of 8)
  char* QKV = alloc((size_t)Hh * sQ * 2);         // QKVp: 48MB = 2 batches x 24MB
  char* KVx = alloc((size_t)Hh * sQ * 2);         //   (Q 8 | K 8 | Vt 8 per batch)
  u16* Vtb = (u16*)alloc((size_t)Hh * sQ * 2);    //   region reused across pairs
  char* Sb = alloc((size_t)Hh * sS * 2);          // 64MB: pair S (2x32MB); FFN2 slabs later
  float* acc1 = (float*)alloc((size_t)BL * Es * 4);
  u16* hbuf = (u16*)alloc((size_t)BL * Ff * 2);   // 32MB: PV bf16 slabs; fp8 h later
  (void)KVx; (void)Vtb; (void)Wkst; (void)Wvst; (void)Wqct; (void)Wkct; (void)Wvct;
  char* QKVp = QKV;
  float* accF = (float*)Sb;   // FFN2 split-K slabs
  float* rsum = (float*)W1t;  // 64 rows x Ls fp32 = 512 KB (self 0..31, cross 32..63)
  char* Wq8 = (char*)Wqst;    // 48 contiguous fp8 head-slabs (x64-scaled)
  char* qn8 = (char*)qn;      // fp8 LN out; kb8/vb8 at +8MB/+16MB (alloc stride)
  char* W1t8 = (char*)W1t;    // fp8 FFN weights (x64), 1MB each
  char* W2t8 = (char*)W2t;
  char* h8 = (char*)hbuf;     // fp8 h (16MB of 32)
  const long tstr = (long)BL * Es * 2;  // 8MB alloc stride between qn/knb/vnb
  (void)in_sizes; (void)n_in; (void)out_size; (void)ws_size;

  const dim3 blk(256);
  transpose6<<<dim3(Dd / 32, Es / 32, 48), blk, 0, stream>>>(Wq_s, Wk_s, Wv_s, Wq_c, Wk_c, Wv_c, Wq8);
  cvt_fp8_kernel<<<dim3((unsigned)(BL * Es / 2048)), blk, 0, stream>>>(k, (char*)knb, BL * Es);
  cvt_fp8_kernel<<<dim3((unsigned)(BL * Es / 2048)), blk, 0, stream>>>(v, (char*)vnb, BL * Es);
  zero_kernel<<<dim3(8 * Hh * Ls / 1024), blk, 0, stream>>>(rsum);

  // LN1 (+ residual copy into acc1), fp8 out
  ln_kernel<1><<<dim3((unsigned)(BL / 4)), blk, 0, stream>>>(q, g1, be1, qn8, acc1, (int)BL);

  const float scl = 0.044194173824159216f;         // 512^-0.5
  const float sclS = scl / 4096.0f;                // weights x64 on both Q and K
  const float aPV = 0.125f / 64.0f;                // 1/H, V x64
  const float aW = 1.0f / 64.0f;                   // FFN weights x64
  const float* np = nullptr;

  // ---- self-attention (causal), per batch-pair p (batches 2p, 2p+1) ----
  for (int p = 0; p < 2; ++p) {
    const char* qp8 = qn8 + (long)p * 2 * sBE;     // pair base (2 batches x 1MB)
    float* rsS = rsum + (long)p * 16 * Ls;
    // pair projection: z = b'*24 + (type*8+h); C = b'*24MB + (z%24)*1MB; Vt transposed
    gemm128<1, 0, 1, 1, false, false, false, false, false, false><<<dim3(4, 16, 48), blk, 0, stream>>>(
        qp8, Wq8, QKVp, np, np, nullptr, Ls, Dd, Es, Es, Es, Dd, Ls, 16,
        sBE, 24, 0, 24, 8,        // A: (z/24)*1MB
        sW, 24, 0, 1,             // B: (z%24)*sW
        24 * sQ, 24, sQ, 24,      // C: (z/24)*24MB + (z%24)*1MB; tz vs z%24
        1.0f);
    // pair S causal: packed triangular grid (136 blocks/slice), z = b'*8 + h
    gemm128<1, 1, 1, 1, false, false, true, false, true, false><<<dim3(136, 1, 16), blk, 0, stream>>>(
        QKVp, QKVp + 8 * sQ, Sb, np, np, rsS, Ls, Ls, Dd, Dd, Dd, Ls, Ls, BIG,
        24 * sQ, 8, sQ, 8, 1,     // A: (z/8)*24MB + (z%8)*1MB
        sQ, 8, 24 * sQ, 8,        // B: (z%8)*1MB + (z/8)*24MB
        8 * sS, 8, sS, 8,         // C: (z/8)*32MB + (z%8)*4MB
        sclS);
    // pair PV (causal Keff clamp via SM==2), DIAG balance, bf16 slabs in hbuf
    gemm128<1, 2, 1, 0, false, false, true, false, false, true><<<dim3(4, 16, 16), blk, 0, stream>>>(
        Sb, QKVp + 16 * sQ, hbuf, np, np, rsS, Ls, Dd, Ls, Ls, Ls, Dd, Ls, BIG,
        8 * sS, 8, sS, 8, 1,      // A: (z/8)*32MB + (z%8)*4MB
        sQ, 8, 24 * sQ, 8,        // B: (z%8)*1MB + (z/8)*24MB
        8 * sQ * 2, 8, sQ * 2, 8, // C: (z/8)*16MB + (z%8)*2MB (bf16)
        aPV);
    reduce8b_kernel<<<dim3(512, 2), blk, 0, stream>>>(hbuf, acc1 + (long)p * 2 * sBE);
  }

  // LN2, fp8 out
  ln_kernel<1><<<dim3((unsigned)(BL / 4)), blk, 0, stream>>>(acc1, g2, be2, qn8, nullptr, (int)BL);

  // ---- cross-attention (non-causal), per batch-pair ----
  for (int p = 0; p < 2; ++p) {
    const char* qp8 = qn8 + (long)p * 2 * sBE;
    float* rsS = rsum + (long)(32 + p * 16) * Ls;
    // pair projection: A = pairbase + b'*1MB + type*8MB (type walks qn|knb|vnb)
    gemm128<1, 0, 1, 1, false, false, false, false, false, false><<<dim3(4, 16, 48), blk, 0, stream>>>(
        qp8, Wq8 + 24 * sW, QKVp, np, np, nullptr, Ls, Dd, Es, Es, Es, Dd, Ls, 16,
        sBE, 24, tstr, 24, 8,     // A: (z/24)*1MB + ((z%24)/8)*8MB
        sW, 24, 0, 1,
        24 * sQ, 24, sQ, 24,
        1.0f);
    gemm128<1, 1, 1, 1, false, false, false, false, false, false><<<dim3(16, 16, 16), blk, 0, stream>>>(
        QKVp, QKVp + 8 * sQ, Sb, np, np, rsS, Ls, Ls, Dd, Dd, Dd, Ls, Ls, BIG,
        24 * sQ, 8, sQ, 8, 1,
        sQ, 8, 24 * sQ, 8,
        8 * sS, 8, sS, 8,
        sclS);
    gemm128<1, 2, 1, 0, false, false, false, false, false, false><<<dim3(4, 16, 16), blk, 0, stream>>>(
        Sb, QKVp + 16 * sQ, hbuf, np, np, rsS, Ls, Dd, Ls, Ls, Ls, Dd, Ls, BIG,
        8 * sS, 8, sS, 8, 1,
        sQ, 8, 24 * sQ, 8,
        8 * sQ * 2, 8, sQ * 2, 8,
        aPV);
    reduce8b_kernel<<<dim3(512, 2), blk, 0, stream>>>(hbuf, acc1 + (long)p * 2 * sBE);
  }

  // FFN weights -> fp8 transposed x64 (rowsum scratch dead now)
  transpose_cvt8<<<dim3(Ff / 32, Es / 32, 1), blk, 0, stream>>>(W1, W1t8, Es, Ff);
  transpose_cvt8<<<dim3(Es / 32, Ff / 32, 1), blk, 0, stream>>>(W2, W2t8, Ff, Es);

  // LN3 (fp8) + FFN (MX fp8)
  ln_kernel<1><<<dim3((unsigned)(BL / 4)), blk, 0, stream>>>(acc1, g3, be3, qn8, nullptr, (int)BL);
  // FFN1: h = relu(x@W1/64 + b1), fp8 store
  gemm128<1, 0, 1, 1, true, true, false, false, false, false><<<dim3(Ff / 128, (unsigned)(BL / 128), 1), blk, 0, stream>>>(
      qn8, W1t8, h8, b1, np, nullptr, (int)BL, Ff, Es, Es, Es, Ff, Ff, BIG,
      0, 1, 0, 1, 1,
      0, 1, 0, 1,
      0, 1, 0, 1, aW);
  // FFN2: split-K=4 (512 elems each), fp32 slabs, alpha=1/64
  gemm128<0, 0, 1, 0, false, false, false, false, false, false><<<dim3(Es / 128, (unsigned)(BL / 128), 4), blk, 0, stream>>>(
      h8, W2t8, accF, np, np, nullptr, (int)BL, Es, 512, Ff, Ff, Es, Es, BIG,
      512, 1, 0, 1, 1,           // A: z*512 bytes (k-offset)
      0, 1, 512, 1,              // B: z*512 bytes (k-offset)
      (long)BL * Es * 4, 1, 0, 1,// C: z*slab
      aW);
  finalize_kernel<<<dim3((unsigned)(BL * Es / 1024)), blk, 0, stream>>>(accF, acc1, b2, (float*)d_out);
}